// Round 4
// baseline (213.843 us; speedup 1.0000x reference)
//
#include <hip/hip_runtime.h>
#include <math.h>

#define BB 16
#define NL 4096
#define NH 1024
#define CL 128
#define CHH 256
#define K0 384
#define K1 256
#define CO 256
#define BN_EPS 1e-5f

typedef __attribute__((ext_vector_type(8))) short bfrag;     // 8 bf16
typedef __attribute__((ext_vector_type(4))) float f32x4;
typedef __attribute__((ext_vector_type(4))) unsigned short ushort4b;

__device__ inline unsigned short f2bf(float f) {
    unsigned int u = __builtin_bit_cast(unsigned int, f);
    u += 0x7fffu + ((u >> 16) & 1u);                 // RNE
    return (unsigned short)(u >> 16);
}
__device__ inline float bf2f(unsigned short h) {
    unsigned int u = ((unsigned int)h) << 16;
    return __builtin_bit_cast(float, u);
}

// ---------------------------------------------------------------------------
// pack candidates: cand4[b*NH+m] = (x, y, z, sum(x^2))
// ---------------------------------------------------------------------------
__global__ __launch_bounds__(256) void k_prep(const float* __restrict__ xyzh,
                                              float4* __restrict__ cand4) {
    int i = blockIdx.x * 256 + threadIdx.x;
    if (i < BB * NH) {
        float x = xyzh[3 * i], y = xyzh[3 * i + 1], z = xyzh[3 * i + 2];
        float ss = __fadd_rn(__fadd_rn(__fmul_rn(x, x), __fmul_rn(y, y)),
                             __fmul_rn(z, z));
        cand4[i] = make_float4(x, y, z, ss);
    }
}

// ---------------------------------------------------------------------------
// transpose feat_high (B, CH, NH) -> fT (B, NH, CH)   (f32, for the gather)
// ---------------------------------------------------------------------------
__global__ __launch_bounds__(256) void k_transpose_fh(const float* __restrict__ fh,
                                                      float* __restrict__ fT) {
    __shared__ float s[32][33];
    int b = blockIdx.z;
    int c0 = blockIdx.y * 32;
    int m0 = blockIdx.x * 32;
    int tx = threadIdx.x % 32, ty = threadIdx.x / 32;
    const float* src = fh + (size_t)b * CHH * NH;
    float* dst = fT + (size_t)b * NH * CHH;
#pragma unroll
    for (int j = 0; j < 4; j++)
        s[ty + 8 * j][tx] = src[(size_t)(c0 + ty + 8 * j) * NH + m0 + tx];
    __syncthreads();
#pragma unroll
    for (int j = 0; j < 4; j++)
        dst[(size_t)(m0 + ty + 8 * j) * CHH + c0 + tx] = s[tx][ty + 8 * j];
}

// ---------------------------------------------------------------------------
// 3-NN search v3: wave = candidate segment (uniform index -> s_load candidates
// into SGPRs, no LDS in hot loop), lane = point. Branchless top-3 on clamped
// d^2 (exact __f*_rn op order as reference), stable merge across segments.
// Block: 256 = 4 waves x 64 points. Grid: (NL/64, B).
// ---------------------------------------------------------------------------
__global__ __launch_bounds__(256) void k_knn(const float* __restrict__ xyzl,
                                             const float4* __restrict__ cand4,
                                             int* __restrict__ idx,
                                             float* __restrict__ wgt) {
    __shared__ float tls[4][64][3];
    __shared__ int   ils[4][64][3];

    int b = blockIdx.y;
    int lane = threadIdx.x & 63;
    int w = __builtin_amdgcn_readfirstlane(threadIdx.x >> 6);   // segment
    int n = blockIdx.x * 64 + lane;

    const float* xl = xyzl + ((size_t)b * NL + n) * 3;
    float l0 = xl[0], l1 = xl[1], l2 = xl[2];
    float a = __fadd_rn(__fadd_rn(__fmul_rn(l0, l0), __fmul_rn(l1, l1)),
                        __fmul_rn(l2, l2));

    const float4* cb = cand4 + (size_t)b * NH + w * 256;   // wave-uniform base

    float t0 = INFINITY, t1 = INFINITY, t2 = INFINITY;
    int i0 = 0, i1 = 0, i2 = 0;
#pragma unroll 4
    for (int j = 0; j < 256; j++) {
        float4 c = cb[j];                                  // uniform -> s_load
        float dot = __fadd_rn(__fadd_rn(__fmul_rn(l0, c.x), __fmul_rn(l1, c.y)),
                              __fmul_rn(l2, c.z));
        float dd = __fsub_rn(__fadd_rn(a, c.w), __fmul_rn(2.0f, dot));
        dd = fmaxf(dd, 0.0f);
        int m = w * 256 + j;
        bool c0 = dd < t0, c1 = dd < t1, c2 = dd < t2;
        t2 = c1 ? t1 : (c2 ? dd : t2);
        i2 = c1 ? i1 : (c2 ? m : i2);
        t1 = c0 ? t0 : (c1 ? dd : t1);
        i1 = c0 ? i0 : (c1 ? m : i1);
        t0 = c0 ? dd : t0;
        i0 = c0 ? m : i0;
    }
    tls[w][lane][0] = t0; tls[w][lane][1] = t1; tls[w][lane][2] = t2;
    ils[w][lane][0] = i0; ils[w][lane][1] = i1; ils[w][lane][2] = i2;
    __syncthreads();

    if (threadIdx.x < 64) {
        int p = threadIdx.x;
        float u0 = tls[0][p][0], u1 = tls[0][p][1], u2 = tls[0][p][2];
        int   j0 = ils[0][p][0], j1 = ils[0][p][1], j2 = ils[0][p][2];
#pragma unroll
        for (int sg = 1; sg < 4; sg++) {
#pragma unroll
            for (int e = 0; e < 3; e++) {
                float dd = tls[sg][p][e];
                int m = ils[sg][p][e];
                bool c0 = dd < u0, c1 = dd < u1, c2 = dd < u2;
                u2 = c1 ? u1 : (c2 ? dd : u2);
                j2 = c1 ? j1 : (c2 ? m : j2);
                u1 = c0 ? u0 : (c1 ? dd : u1);
                j1 = c0 ? j0 : (c1 ? m : j1);
                u0 = c0 ? dd : u0;
                j0 = c0 ? m : j0;
            }
        }
        float d0 = sqrtf(u0), d1 = sqrtf(u1), d2 = sqrtf(u2);
        float w0 = 1.0f / fmaxf(d0, 1e-8f);
        float w1 = 1.0f / fmaxf(d1, 1e-8f);
        float w2 = 1.0f / fmaxf(d2, 1e-8f);
        float wsum = __fadd_rn(__fadd_rn(w0, w1), w2);
        w0 /= wsum; w1 /= wsum; w2 /= wsum;
        int nn = blockIdx.x * 64 + p;
        size_t base = ((size_t)b * NL + nn) * 3;
        idx[base] = j0; idx[base + 1] = j1; idx[base + 2] = j2;
        wgt[base] = w0; wgt[base + 1] = w1; wgt[base + 2] = w2;
    }
}

// ---------------------------------------------------------------------------
// interpolate -> Xb[b][n][c] bf16, c in [0, 256)
// ---------------------------------------------------------------------------
__global__ __launch_bounds__(256) void k_interp(const float* __restrict__ fT,
                                                const int* __restrict__ idx,
                                                const float* __restrict__ wgt,
                                                unsigned short* __restrict__ Xb) {
    int b = blockIdx.y;
    int n0 = blockIdx.x * 16;
    int c = threadIdx.x;
    const float* fTb = fT + (size_t)b * NH * CHH;
    for (int j = 0; j < 16; j++) {
        size_t base = ((size_t)b * NL + n0 + j) * 3;
        int m0 = idx[base], m1 = idx[base + 1], m2 = idx[base + 2];
        float w0 = wgt[base], w1 = wgt[base + 1], w2 = wgt[base + 2];
        float f = __fadd_rn(__fadd_rn(__fmul_rn(w0, fTb[(size_t)m0 * CHH + c]),
                                      __fmul_rn(w1, fTb[(size_t)m1 * CHH + c])),
                            __fmul_rn(w2, fTb[(size_t)m2 * CHH + c]));
        Xb[((size_t)b * NL + n0 + j) * K0 + c] = f2bf(f);
    }
}

// ---------------------------------------------------------------------------
// feat_low (B, CL, NL) f32 -> Xb[b][n][256 + c] bf16   (transpose-convert)
// ---------------------------------------------------------------------------
__global__ __launch_bounds__(256) void k_fl_t(const float* __restrict__ fl,
                                              unsigned short* __restrict__ Xb) {
    __shared__ unsigned short s[32][68];
    int b = blockIdx.z, c0 = blockIdx.y * 32, n0 = blockIdx.x * 64;
    int tx = threadIdx.x & 63, ty = threadIdx.x >> 6;       // 64 x 4
    const float* src = fl + ((size_t)b * CL + c0) * NL + n0;
#pragma unroll
    for (int i = 0; i < 8; i++) {
        int c = ty * 8 + i;
        s[c][tx] = f2bf(src[(size_t)c * NL + tx]);
    }
    __syncthreads();
    int n = threadIdx.x >> 2, q = threadIdx.x & 3;
    ushort4b o0, o1;
#pragma unroll
    for (int e = 0; e < 4; e++) o0[e] = s[q * 8 + e][n];
#pragma unroll
    for (int e = 0; e < 4; e++) o1[e] = s[q * 8 + 4 + e][n];
    unsigned short* dst = Xb + ((size_t)b * NL + n0 + n) * K0 + CHH + c0 + q * 8;
    *(ushort4b*)dst = o0;
    *(ushort4b*)(dst + 4) = o1;
}

// ---------------------------------------------------------------------------
// f32 -> bf16 convert (weights)
// ---------------------------------------------------------------------------
__global__ __launch_bounds__(256) void k_cvt(const float* __restrict__ src,
                                             unsigned short* __restrict__ dst, int n) {
    int i = blockIdx.x * 256 + threadIdx.x;
    if (i < n) dst[i] = f2bf(src[i]);
}

// ---------------------------------------------------------------------------
// MFMA GEMM: Y[b][n][m] = bf16( sum_k W[m][k]*X[n][k] + bias[m] )
// 128x128 tile, BK=32, 4 waves (64x64 each), XOR-swizzled LDS, double buffer.
// ---------------------------------------------------------------------------
__device__ inline int swz(int r, int cb) {
    return r * 32 + ((cb ^ ((r >> 1) & 3)) << 3);   // short index, 16B blocks
}

template <int K>
__global__ __launch_bounds__(256) void k_gemmb(const unsigned short* __restrict__ X,
                                               const unsigned short* __restrict__ Wb,
                                               const float* __restrict__ bias,
                                               unsigned short* __restrict__ Y) {
    __shared__ __align__(16) unsigned short sA[2][128 * 32];
    __shared__ __align__(16) unsigned short sB[2][128 * 32];

    int b  = blockIdx.z;
    int m0 = blockIdx.y * 128;
    int n0 = blockIdx.x * 128;
    int tid = threadIdx.x;
    int lane = tid & 63;
    int wid = tid >> 6;
    int wm = wid >> 1, wn = wid & 1;

    int sr = tid >> 2;          // staging row 0..63 (and +64)
    int scb = tid & 3;          // staging 16B block
    int swA0 = swz(sr, scb), swA1 = swz(sr + 64, scb);

    const unsigned short* Wt = Wb + (size_t)m0 * K + scb * 8;
    const unsigned short* Xt = X + ((size_t)b * NL + n0) * K + scb * 8;

    f32x4 acc[4][4] = {};

    bfrag a0 = *(const bfrag*)&Wt[(size_t)sr * K];
    bfrag a1 = *(const bfrag*)&Wt[(size_t)(sr + 64) * K];
    bfrag b0 = *(const bfrag*)&Xt[(size_t)sr * K];
    bfrag b1 = *(const bfrag*)&Xt[(size_t)(sr + 64) * K];
    *(bfrag*)&sA[0][swA0] = a0;
    *(bfrag*)&sA[0][swA1] = a1;
    *(bfrag*)&sB[0][swA0] = b0;
    *(bfrag*)&sB[0][swA1] = b1;
    __syncthreads();

    const int nkt = K / 32;
    int cur = 0;
#pragma unroll 2
    for (int t = 0; t < nkt; t++) {
        bfrag na0, na1, nb0, nb1;
        bool more = (t + 1 < nkt);
        if (more) {
            int kk = (t + 1) * 32;
            na0 = *(const bfrag*)&Wt[(size_t)sr * K + kk];
            na1 = *(const bfrag*)&Wt[(size_t)(sr + 64) * K + kk];
            nb0 = *(const bfrag*)&Xt[(size_t)sr * K + kk];
            nb1 = *(const bfrag*)&Xt[(size_t)(sr + 64) * K + kk];
        }
        bfrag af[4], bf[4];
#pragma unroll
        for (int mi = 0; mi < 4; mi++) {
            int r = wm * 64 + mi * 16 + (lane & 15);
            af[mi] = *(const bfrag*)&sA[cur][swz(r, lane >> 4)];
        }
#pragma unroll
        for (int ni = 0; ni < 4; ni++) {
            int r = wn * 64 + ni * 16 + (lane & 15);
            bf[ni] = *(const bfrag*)&sB[cur][swz(r, lane >> 4)];
        }
#pragma unroll
        for (int mi = 0; mi < 4; mi++)
#pragma unroll
            for (int ni = 0; ni < 4; ni++)
                acc[mi][ni] = __builtin_amdgcn_mfma_f32_16x16x32_bf16(
                    af[mi], bf[ni], acc[mi][ni], 0, 0, 0);
        if (more) {
            *(bfrag*)&sA[cur ^ 1][swA0] = na0;
            *(bfrag*)&sA[cur ^ 1][swA1] = na1;
            *(bfrag*)&sB[cur ^ 1][swA0] = nb0;
            *(bfrag*)&sB[cur ^ 1][swA1] = nb1;
            __syncthreads();
            cur ^= 1;
        }
    }

    // C frag: col = lane&15 (n), row = (lane>>4)*4 + j (m)
    int col = lane & 15, rg = (lane >> 4) << 2;
#pragma unroll
    for (int mi = 0; mi < 4; mi++) {
        int m = m0 + wm * 64 + mi * 16 + rg;
        f32x4 bv = *(const f32x4*)&bias[m];
#pragma unroll
        for (int ni = 0; ni < 4; ni++) {
            int n = n0 + wn * 64 + ni * 16 + col;
            f32x4 c = acc[mi][ni];
            unsigned short* dst = Y + ((size_t)b * NL + n) * CO + m;
            ushort4b o;
            o[0] = f2bf(c[0] + bv[0]); o[1] = f2bf(c[1] + bv[1]);
            o[2] = f2bf(c[2] + bv[2]); o[3] = f2bf(c[3] + bv[3]);
            *(ushort4b*)dst = o;
        }
    }
}

// ---------------------------------------------------------------------------
// stats over n-major bf16 (65536 rows x 256 ch) -> atomic partial sums
// ---------------------------------------------------------------------------
__global__ __launch_bounds__(256) void k_stats(const unsigned short* __restrict__ y,
                                               float* __restrict__ psum,
                                               float* __restrict__ psq) {
    int r0 = blockIdx.x * 256;
    int lane = threadIdx.x & 63, wid = threadIdx.x >> 6;
    float s[4] = {0, 0, 0, 0}, q[4] = {0, 0, 0, 0};
    for (int j = 0; j < 64; j++) {
        int r = r0 + wid * 64 + j;
        ushort4b v = *(const ushort4b*)&y[(size_t)r * CO + lane * 4];
#pragma unroll
        for (int e = 0; e < 4; e++) {
            float f = bf2f(v[e]);
            s[e] += f; q[e] += f * f;
        }
    }
    __shared__ float ls[4][256], lq[4][256];
#pragma unroll
    for (int e = 0; e < 4; e++) {
        ls[wid][lane * 4 + e] = s[e];
        lq[wid][lane * 4 + e] = q[e];
    }
    __syncthreads();
    int c = threadIdx.x;
    float S = ls[0][c] + ls[1][c] + ls[2][c] + ls[3][c];
    float Q = lq[0][c] + lq[1][c] + lq[2][c] + lq[3][c];
    atomicAdd(&psum[c], S);
    atomicAdd(&psq[c], Q);
}

__global__ void k_fin(const float* __restrict__ psum, const float* __restrict__ psq,
                      const float* __restrict__ gamma, const float* __restrict__ beta,
                      float* __restrict__ scale, float* __restrict__ shift) {
    int c = threadIdx.x;
    float N = (float)(BB * NL);
    float mean = psum[c] / N;
    float var = psq[c] / N - mean * mean;
    float sc = gamma[c] / sqrtf(var + BN_EPS);
    scale[c] = sc;
    shift[c] = beta[c] - mean * sc;
}

// ---------------------------------------------------------------------------
// BN0 + ReLU in place on n-major bf16 y0
// ---------------------------------------------------------------------------
__global__ __launch_bounds__(256) void k_bn0(unsigned short* __restrict__ y,
                                             const float* __restrict__ scale,
                                             const float* __restrict__ shift) {
    size_t i = (size_t)blockIdx.x * 256 + threadIdx.x;      // short8 index
    unsigned short* p = y + i * 8;
    int cb = (int)(i & 31) * 8;
    bfrag v = *(bfrag*)p;
    f32x4 s0 = *(const f32x4*)&scale[cb], s1 = *(const f32x4*)&scale[cb + 4];
    f32x4 h0 = *(const f32x4*)&shift[cb], h1 = *(const f32x4*)&shift[cb + 4];
    bfrag o;
#pragma unroll
    for (int e = 0; e < 4; e++)
        o[e] = (short)f2bf(fmaxf(fmaf(s0[e], bf2f((unsigned short)v[e]), h0[e]), 0.f));
#pragma unroll
    for (int e = 0; e < 4; e++)
        o[4 + e] = (short)f2bf(fmaxf(fmaf(s1[e], bf2f((unsigned short)v[4 + e]), h1[e]), 0.f));
    *(bfrag*)p = o;
}

// ---------------------------------------------------------------------------
// final: read y1 bf16 [b][n][m], BN1+ReLU, transpose-write f32 out [b][m][n]
// tile 64n x 64m, 256 threads
// ---------------------------------------------------------------------------
__global__ __launch_bounds__(256) void k_out(const unsigned short* __restrict__ y1,
                                             const float* __restrict__ scale,
                                             const float* __restrict__ shift,
                                             float* __restrict__ out) {
    __shared__ float s[64][65];
    int b = blockIdx.z, m0 = blockIdx.y * 64, n0 = blockIdx.x * 64;
    int r = threadIdx.x >> 3;            // 0..31
    int mq = (threadIdx.x & 7) * 8;      // 0..56
#pragma unroll
    for (int it = 0; it < 2; it++) {
        int row = r + it * 32;
        bfrag v = *(const bfrag*)&y1[((size_t)b * NL + n0 + row) * CO + m0 + mq];
#pragma unroll
        for (int e = 0; e < 8; e++) {
            int m = mq + e;
            float f = bf2f((unsigned short)v[e]);
            s[m][row] = fmaxf(fmaf(scale[m0 + m], f, shift[m0 + m]), 0.f);
        }
    }
    __syncthreads();
    int m = threadIdx.x >> 2, nb = (threadIdx.x & 3) * 16;
    float* orow = out + ((size_t)b * CO + m0 + m) * NL + n0 + nb;
#pragma unroll
    for (int i = 0; i < 16; i += 4) {
        float4 v = make_float4(s[m][nb + i], s[m][nb + i + 1],
                               s[m][nb + i + 2], s[m][nb + i + 3]);
        *(float4*)&orow[i] = v;
    }
}

// ---------------------------------------------------------------------------
extern "C" void kernel_launch(void* const* d_in, const int* in_sizes, int n_in,
                              void* d_out, int out_size, void* d_ws, size_t ws_size,
                              hipStream_t stream) {
    const float* xyz_low   = (const float*)d_in[0];
    const float* xyz_high  = (const float*)d_in[1];
    const float* feat_low  = (const float*)d_in[2];
    const float* feat_high = (const float*)d_in[3];
    const float* W0  = (const float*)d_in[4];
    const float* b0  = (const float*)d_in[5];
    const float* g0  = (const float*)d_in[6];
    const float* be0 = (const float*)d_in[7];
    const float* W1  = (const float*)d_in[8];
    const float* b1  = (const float*)d_in[9];
    const float* g1  = (const float*)d_in[10];
    const float* be1 = (const float*)d_in[11];
    float* out = (float*)d_out;

    char* ws = (char*)d_ws;
    // [Xb 48MB][y0 32MB][y1 32MB (fT aliases first 16MB; fT dead before gemm1)]
    // [tail: idx, wgt, cand4, Wb0, Wb1, psums, scales]
    unsigned short* Xb  = (unsigned short*)ws;
    unsigned short* y0  = (unsigned short*)(ws + ((size_t)48 << 20));
    unsigned short* y1  = (unsigned short*)(ws + ((size_t)80 << 20));
    float* fT           = (float*)(ws + ((size_t)80 << 20));
    char* tail          = ws + ((size_t)112 << 20);
    int*    idx   = (int*)tail;                       // 768 KB
    float*  wgt   = (float*)(tail + 786432);          // 768 KB
    float4* cand4 = (float4*)(tail + 2 * 786432);     // 256 KB
    unsigned short* Wb0 = (unsigned short*)(tail + 2 * 786432 + 262144);
    unsigned short* Wb1 = Wb0 + CO * K0;
    float* prm    = (float*)(Wb1 + CO * K1);
    float* psum0 = prm,        *psq0 = prm + 256;
    float* psum1 = prm + 512,  *psq1 = prm + 768;
    float* scale0 = prm + 1024, *shift0 = prm + 1280;
    float* scale1 = prm + 1536, *shift1 = prm + 1792;

    k_cvt<<<(CO * K0 + 255) / 256, 256, 0, stream>>>(W0, Wb0, CO * K0);
    k_cvt<<<(CO * K1 + 255) / 256, 256, 0, stream>>>(W1, Wb1, CO * K1);
    k_prep<<<(BB * NH + 255) / 256, 256, 0, stream>>>(xyz_high, cand4);
    k_transpose_fh<<<dim3(NH / 32, CHH / 32, BB), 256, 0, stream>>>(feat_high, fT);
    k_knn<<<dim3(NL / 64, BB), 256, 0, stream>>>(xyz_low, cand4, idx, wgt);
    k_interp<<<dim3(NL / 16, BB), 256, 0, stream>>>(fT, idx, wgt, Xb);
    k_fl_t<<<dim3(NL / 64, CL / 32, BB), 256, 0, stream>>>(feat_low, Xb);
    hipMemsetAsync(prm, 0, 1024 * sizeof(float), stream);

    k_gemmb<K0><<<dim3(NL / 128, CO / 128, BB), 256, 0, stream>>>(Xb, Wb0, b0, y0);
    k_stats<<<256, 256, 0, stream>>>(y0, psum0, psq0);
    k_fin<<<1, 256, 0, stream>>>(psum0, psq0, g0, be0, scale0, shift0);
    k_bn0<<<(BB * NL * CO / 8) / 256, 256, 0, stream>>>(y0, scale0, shift0);
    k_gemmb<K1><<<dim3(NL / 128, CO / 128, BB), 256, 0, stream>>>(y0, Wb1, b1, y1);
    k_stats<<<256, 256, 0, stream>>>(y1, psum1, psq1);
    k_fin<<<1, 256, 0, stream>>>(psum1, psq1, g1, be1, scale1, shift1);
    k_out<<<dim3(NL / 64, CO / 64, BB), 256, 0, stream>>>(y1, scale1, shift1, out);
}